// Round 1
// baseline (47847.919 us; speedup 1.0000x reference)
//
#include <hip/hip_runtime.h>

// Problem constants (from reference)
#define BB    2048
#define TT    100
#define CC    8
#define HD    64
#define HHD   128
#define OO    10
#define MROWS 8      // batch rows per block; grid = BB/MROWS = 256 blocks, 1/CU

__device__ __forceinline__ float fast_tanh(float x) {
  // 1 - 2/(e^{2x}+1): monotone-safe at +/-inf (no inf/inf NaN), ~1e-7 abs err
  float e = __expf(2.0f * x);
  return 1.0f - 2.0f / (e + 1.0f);
}

__global__ void zero_out_k(float* o) {
  if (threadIdx.x < 2) o[threadIdx.x] = 0.0f;
}

// Hidden layer: IN[8][128] @ Wh(2 cols x 32 k in regs) -> partial sums in LDS.
// thread = (cp = t&63 -> cols 2cp,2cp+1 ; q = t>>6 -> k in [32q,32q+32))
__device__ __forceinline__ void hidden_partial(const float2 (&wh)[32],
                                               const float (*in)[HHD],
                                               float* part, int cp, int q) {
  float2 hacc[MROWS];
#pragma unroll
  for (int r = 0; r < MROWS; ++r) hacc[r] = make_float2(0.f, 0.f);
#pragma unroll
  for (int kt = 0; kt < 8; ++kt) {
    const float2 w0 = wh[kt*4+0], w1 = wh[kt*4+1], w2 = wh[kt*4+2], w3 = wh[kt*4+3];
#pragma unroll
    for (int r = 0; r < MROWS; ++r) {
      const float4 hv = *(const float4*)&in[r][q*32 + kt*4];   // wave-broadcast
      hacc[r].x = fmaf(hv.x, w0.x, hacc[r].x); hacc[r].y = fmaf(hv.x, w0.y, hacc[r].y);
      hacc[r].x = fmaf(hv.y, w1.x, hacc[r].x); hacc[r].y = fmaf(hv.y, w1.y, hacc[r].y);
      hacc[r].x = fmaf(hv.z, w2.x, hacc[r].x); hacc[r].y = fmaf(hv.z, w2.y, hacc[r].y);
      hacc[r].x = fmaf(hv.w, w3.x, hacc[r].x); hacc[r].y = fmaf(hv.w, w3.y, hacc[r].y);
    }
  }
#pragma unroll
  for (int r = 0; r < MROWS; ++r)
    *(float2*)&part[(q*MROWS + r)*HHD + 2*cp] = hacc[r];
}

// Combine 4 k-quarter partials + bias + relu -> out buffer
__device__ __forceinline__ void hidden_reduce(const float* part, const float* bias_g,
                                              float (*outb)[HHD], int t) {
  const int n = t & 127, rg = t >> 7;       // rg in {0,1} -> 4 rows each
  const float b = bias_g[n];                // global, L1-hot
#pragma unroll
  for (int rr = 0; rr < 4; ++rr) {
    const int r = rg*4 + rr;
    float sm = part[(0*MROWS + r)*HHD + n] + part[(1*MROWS + r)*HHD + n]
             + part[(2*MROWS + r)*HHD + n] + part[(3*MROWS + r)*HHD + n] + b;
    outb[r][n] = fmaxf(sm, 0.f);
  }
}

__global__ void __launch_bounds__(256, 1)
cde_main(const float* __restrict__ coeffs, const int* __restrict__ yy,
         const float* __restrict__ times,
         const float* __restrict__ W_init, const float* __restrict__ b_init,
         const float* __restrict__ W_in,  const float* __restrict__ b_in,
         const float* __restrict__ W_h,   const float* __restrict__ b_h,
         const float* __restrict__ W_out, const float* __restrict__ b_out,
         const float* __restrict__ W_read,const float* __restrict__ b_read,
         float* __restrict__ out)
{
  __shared__ float sWin[HD * HHD];          // 32KB, [k][n]
  __shared__ float sH0[MROWS][HHD];         // 4KB
  __shared__ float sH1[MROWS][HHD];         // 4KB
  __shared__ float sPart[4*MROWS*HHD];      // 16KB
  __shared__ float sZs[MROWS][HD];          // 2KB  (stage input z)
  __shared__ float sDx[MROWS][CC];
  __shared__ float sLog[MROWS][OO];

  const int t    = threadIdx.x;
  const int row0 = blockIdx.x * MROWS;
  const int cp   = t & 63;
  const int qq   = t >> 6;

  // ---- stage W_in into LDS (coalesced float4) ----
  {
    const float4* src = (const float4*)W_in;
    float4* dst = (float4*)sWin;
#pragma unroll
    for (int i = 0; i < 8; ++i) dst[t + 256*i] = src[t + 256*i];
  }

  // ---- register-resident weights ----
  float2 wout[128];                          // W_out cols (2t, 2t+1), all 128 k
#pragma unroll
  for (int k = 0; k < 128; ++k)
    wout[k] = *(const float2*)(W_out + k*(HD*CC) + 2*t);

  float2 whA[32], whB[32];                   // W_h[l] cols (2cp,2cp+1), k-quarter qq
#pragma unroll
  for (int kk = 0; kk < 32; ++kk) {
    whA[kk] = *(const float2*)(W_h + ((32*qq + kk)*HHD + 2*cp));
    whB[kk] = *(const float2*)(W_h + (HHD*HHD + (32*qq + kk)*HHD + 2*cp));
  }
  const float2 binv  = *(const float2*)(b_in  + 2*cp);
  const float2 boutv = *(const float2*)(b_out + 2*t);

  // owner lane (t%4==0) keeps z and RK accumulator for (all rows r, h = t/4)
  const bool owner = ((t & 3) == 0);
  const int  hown  = t >> 2;
  float z0r[MROWS], kacc[MROWS];

  if (owner) {
#pragma unroll
    for (int r = 0; r < MROWS; ++r) {
      const float* cf = coeffs + (size_t)(row0 + r) * (TT*CC);
      float a = b_init[hown];
#pragma unroll
      for (int c = 0; c < CC; ++c) a = fmaf(cf[c], W_init[c*HD + hown], a);
      z0r[r] = a;
      sZs[r][hown] = a;
    }
  }

  for (int step = 0; step < TT-1; ++step) {
    __syncthreads();                          // protect sDx/sZs from prior readers
    const float dti = times[step+1] - times[step];
    if (t < 64) {
      const int r = t >> 3, c = t & 7;
      const float* cf = coeffs + (size_t)(row0 + r)*(TT*CC) + step*CC + c;
      sDx[r][c] = (cf[CC] - cf[0]) / dti;
    }

    for (int s = 0; s < 4; ++s) {
      __syncthreads();                        // sZs (+sDx) visible

      // ---- layer A: relu(sZs[8][64] @ W_in + b_in) -> sH0[8][128] ----
      {
        const int rg = t >> 6;                // wave-uniform
        const int r0 = rg * 2;
        float2 a0 = make_float2(0.f,0.f), a1 = make_float2(0.f,0.f);
#pragma unroll
        for (int k = 0; k < HD; k += 4) {
          const float4 zv0 = *(const float4*)&sZs[r0  ][k];   // broadcast
          const float4 zv1 = *(const float4*)&sZs[r0+1][k];
          const float2 w0 = *(const float2*)&sWin[(k+0)*HHD + 2*cp];
          const float2 w1 = *(const float2*)&sWin[(k+1)*HHD + 2*cp];
          const float2 w2 = *(const float2*)&sWin[(k+2)*HHD + 2*cp];
          const float2 w3 = *(const float2*)&sWin[(k+3)*HHD + 2*cp];
          a0.x = fmaf(zv0.x, w0.x, a0.x); a0.y = fmaf(zv0.x, w0.y, a0.y);
          a0.x = fmaf(zv0.y, w1.x, a0.x); a0.y = fmaf(zv0.y, w1.y, a0.y);
          a0.x = fmaf(zv0.z, w2.x, a0.x); a0.y = fmaf(zv0.z, w2.y, a0.y);
          a0.x = fmaf(zv0.w, w3.x, a0.x); a0.y = fmaf(zv0.w, w3.y, a0.y);
          a1.x = fmaf(zv1.x, w0.x, a1.x); a1.y = fmaf(zv1.x, w0.y, a1.y);
          a1.x = fmaf(zv1.y, w1.x, a1.x); a1.y = fmaf(zv1.y, w1.y, a1.y);
          a1.x = fmaf(zv1.z, w2.x, a1.x); a1.y = fmaf(zv1.z, w2.y, a1.y);
          a1.x = fmaf(zv1.w, w3.x, a1.x); a1.y = fmaf(zv1.w, w3.y, a1.y);
        }
        a0.x = fmaxf(a0.x + binv.x, 0.f); a0.y = fmaxf(a0.y + binv.y, 0.f);
        a1.x = fmaxf(a1.x + binv.x, 0.f); a1.y = fmaxf(a1.y + binv.y, 0.f);
        *(float2*)&sH0[r0  ][2*cp] = a0;
        *(float2*)&sH0[r0+1][2*cp] = a1;
      }
      __syncthreads();

      // ---- hidden 1: sH0 -> sPart -> sH1 ----
      hidden_partial(whA, sH0, sPart, cp, qq);
      __syncthreads();
      hidden_reduce(sPart, b_h, sH1, t);
      __syncthreads();

      // ---- hidden 2: sH1 -> sPart -> sH0 ----
      hidden_partial(whB, sH1, sPart, cp, qq);
      __syncthreads();
      hidden_reduce(sPart, b_h + HHD, sH0, t);
      __syncthreads();

      // ---- big layer (h @ W_out) + tanh + einsum + RK update ----
      {
        float2 acc[MROWS];
#pragma unroll
        for (int r = 0; r < MROWS; ++r) acc[r] = make_float2(0.f, 0.f);
#pragma unroll
        for (int kt = 0; kt < 32; ++kt) {
          const float2 w0 = wout[kt*4+0], w1 = wout[kt*4+1];
          const float2 w2 = wout[kt*4+2], w3 = wout[kt*4+3];
#pragma unroll
          for (int r = 0; r < MROWS; ++r) {
            const float4 hv = *(const float4*)&sH0[r][kt*4];   // broadcast
            acc[r].x = fmaf(hv.x, w0.x, acc[r].x); acc[r].y = fmaf(hv.x, w0.y, acc[r].y);
            acc[r].x = fmaf(hv.y, w1.x, acc[r].x); acc[r].y = fmaf(hv.y, w1.y, acc[r].y);
            acc[r].x = fmaf(hv.z, w2.x, acc[r].x); acc[r].y = fmaf(hv.z, w2.y, acc[r].y);
            acc[r].x = fmaf(hv.w, w3.x, acc[r].x); acc[r].y = fmaf(hv.w, w3.y, acc[r].y);
          }
        }
        // cols (2t,2t+1): h = t/4, c0 = (2t)%8
        const int c0 = (2*t) & 7;
#pragma unroll
        for (int r = 0; r < MROWS; ++r) {
          const float u0 = acc[r].x + boutv.x;
          const float u1 = acc[r].y + boutv.y;
          float p = fast_tanh(u0) * sDx[r][c0] + fast_tanh(u1) * sDx[r][c0+1];
          p += __shfl_xor(p, 1);
          p += __shfl_xor(p, 2);
          if (owner) {
            const float g = p;                          // k_{s+1}[r][hown]
            if (s == 0)      kacc[r] = g;
            else if (s == 3) kacc[r] += g;
            else             kacc[r] += 2.0f * g;
            float zs;
            if (s == 3) {
              const float zn = z0r[r] + dti * (1.0f/6.0f) * kacc[r];
              z0r[r] = zn; zs = zn;
            } else {
              zs = z0r[r] + ((s == 2) ? dti : 0.5f * dti) * g;
            }
            sZs[r][hown] = zs;
          }
        }
      }
    } // stages
  }   // steps

  __syncthreads();
  // ---- readout: logits = zT @ W_read + b_read ----
  if (t < MROWS * OO) {
    const int r = t / OO, o = t % OO;
    float a = b_read[o];
#pragma unroll 8
    for (int k = 0; k < HD; ++k) a = fmaf(sZs[r][k], W_read[k*OO + o], a);
    sLog[r][o] = a;
  }
  __syncthreads();
  if (t < 64) {
    float lv = 0.f, cv = 0.f;
    if (t < MROWS) {
      const int r = t;
      float mx = sLog[r][0]; int am = 0;
#pragma unroll
      for (int o = 1; o < OO; ++o) { const float v = sLog[r][o]; if (v > mx) { mx = v; am = o; } }
      float se = 0.f;
#pragma unroll
      for (int o = 0; o < OO; ++o) se += expf(sLog[r][o] - mx);
      const float lse = mx + logf(se);
      const int yr = yy[row0 + r];
      lv = (lse - sLog[r][yr]) * (1.0f / (float)BB);
      cv = (am == yr) ? 1.0f : 0.0f;
    }
    lv += __shfl_xor(lv, 1); lv += __shfl_xor(lv, 2); lv += __shfl_xor(lv, 4);
    cv += __shfl_xor(cv, 1); cv += __shfl_xor(cv, 2); cv += __shfl_xor(cv, 4);
    if (t == 0) { atomicAdd(&out[0], lv); atomicAdd(&out[1], cv); }
  }
}

extern "C" void kernel_launch(void* const* d_in, const int* in_sizes, int n_in,
                              void* d_out, int out_size, void* d_ws, size_t ws_size,
                              hipStream_t stream) {
  const float* coeffs = (const float*)d_in[0];
  const int*   y      = (const int*)  d_in[1];
  const float* times  = (const float*)d_in[2];
  const float* W_init = (const float*)d_in[3];
  const float* b_init = (const float*)d_in[4];
  const float* W_in   = (const float*)d_in[5];
  const float* b_in   = (const float*)d_in[6];
  const float* W_h    = (const float*)d_in[7];
  const float* b_h    = (const float*)d_in[8];
  const float* W_out  = (const float*)d_in[9];
  const float* b_out  = (const float*)d_in[10];
  const float* W_read = (const float*)d_in[11];
  const float* b_read = (const float*)d_in[12];
  float* out = (float*)d_out;

  zero_out_k<<<1, 64, 0, stream>>>(out);   // d_out is poisoned 0xAA before every replay
  cde_main<<<BB/MROWS, 256, 0, stream>>>(coeffs, y, times, W_init, b_init,
                                         W_in, b_in, W_h, b_h, W_out, b_out,
                                         W_read, b_read, out);
}

// Round 2
// 23453.674 us; speedup vs baseline: 2.0401x; 2.0401x over previous
//
#include <hip/hip_runtime.h>

// Problem constants (from reference)
#define BB    2048
#define TT    100
#define CC    8
#define HD    64
#define HHD   128
#define OO    10
#define MROWS 8      // batch rows per block; grid = BB/MROWS = 256 blocks, 1/CU
#define NTHR  512    // 8 waves/CU; full 256-VGPR file per thread slot

__device__ __forceinline__ float fast_tanh(float x) {
  float e = __expf(2.0f * x);
  return 1.0f - 2.0f / (e + 1.0f);
}

__global__ void zero_out_k(float* o) {
  if (threadIdx.x < 2) o[threadIdx.x] = 0.0f;
}

// Hidden layer k-slice: in[8][128] (broadcast reads) x wh(2 cols, 16 k) -> ds_add into part
__device__ __forceinline__ void hidden_adds(const float2 (&wh)[16],
                                            const float (*in)[HHD],
                                            float (*part)[HHD],
                                            int cp, int kb) {
#pragma unroll
  for (int r = 0; r < MROWS; ++r) {
    const float4 h0 = *(const float4*)&in[r][kb+0];    // wave-uniform addr -> broadcast
    const float4 h1 = *(const float4*)&in[r][kb+4];
    const float4 h2 = *(const float4*)&in[r][kb+8];
    const float4 h3 = *(const float4*)&in[r][kb+12];
    float a0 = 0.f, a1 = 0.f;
    a0 = fmaf(h0.x, wh[ 0].x, a0); a1 = fmaf(h0.x, wh[ 0].y, a1);
    a0 = fmaf(h0.y, wh[ 1].x, a0); a1 = fmaf(h0.y, wh[ 1].y, a1);
    a0 = fmaf(h0.z, wh[ 2].x, a0); a1 = fmaf(h0.z, wh[ 2].y, a1);
    a0 = fmaf(h0.w, wh[ 3].x, a0); a1 = fmaf(h0.w, wh[ 3].y, a1);
    a0 = fmaf(h1.x, wh[ 4].x, a0); a1 = fmaf(h1.x, wh[ 4].y, a1);
    a0 = fmaf(h1.y, wh[ 5].x, a0); a1 = fmaf(h1.y, wh[ 5].y, a1);
    a0 = fmaf(h1.z, wh[ 6].x, a0); a1 = fmaf(h1.z, wh[ 6].y, a1);
    a0 = fmaf(h1.w, wh[ 7].x, a0); a1 = fmaf(h1.w, wh[ 7].y, a1);
    a0 = fmaf(h2.x, wh[ 8].x, a0); a1 = fmaf(h2.x, wh[ 8].y, a1);
    a0 = fmaf(h2.y, wh[ 9].x, a0); a1 = fmaf(h2.y, wh[ 9].y, a1);
    a0 = fmaf(h2.z, wh[10].x, a0); a1 = fmaf(h2.z, wh[10].y, a1);
    a0 = fmaf(h2.w, wh[11].x, a0); a1 = fmaf(h2.w, wh[11].y, a1);
    a0 = fmaf(h3.x, wh[12].x, a0); a1 = fmaf(h3.x, wh[12].y, a1);
    a0 = fmaf(h3.y, wh[13].x, a0); a1 = fmaf(h3.y, wh[13].y, a1);
    a0 = fmaf(h3.z, wh[14].x, a0); a1 = fmaf(h3.z, wh[14].y, a1);
    a0 = fmaf(h3.w, wh[15].x, a0); a1 = fmaf(h3.w, wh[15].y, a1);
    atomicAdd(&part[r][2*cp],   a0);                   // ds_add_f32, lanes contiguous
    atomicAdd(&part[r][2*cp+1], a1);
  }
}

__global__ void __launch_bounds__(NTHR)
cde_main(const float* __restrict__ coeffs, const int* __restrict__ yy,
         const float* __restrict__ times,
         const float* __restrict__ W_init, const float* __restrict__ b_init,
         const float* __restrict__ W_in,  const float* __restrict__ b_in,
         const float* __restrict__ W_h,   const float* __restrict__ b_h,
         const float* __restrict__ W_out, const float* __restrict__ b_out,
         const float* __restrict__ W_read,const float* __restrict__ b_read,
         float* __restrict__ out)
{
  __shared__ float sZs[MROWS][HD];        // 2KB   stage-input z
  __shared__ float sHa[MROWS][HHD];       // 4KB   activations (A-out / h2-out)
  __shared__ float sHb[MROWS][HHD];       // 4KB   activations (h1-out)
  __shared__ float pA [MROWS][HHD];       // 4KB   ds_add target, layer A (bias-primed)
  __shared__ float p1 [MROWS][HHD];       // 4KB   ds_add target, hidden1
  __shared__ float p2 [MROWS][HHD];       // 4KB   ds_add target, hidden2
  __shared__ float pB [MROWS][576];       // 18KB  ds_add target, big layer (9h+cc pad)
  __shared__ float sDx[MROWS][CC];
  __shared__ float sLog[MROWS][OO];

  const int t    = threadIdx.x;
  const int row0 = blockIdx.x * MROWS;
  const int cp   = t & 63;        // A/hidden col-pair -> cols 2cp,2cp+1
  const int ks8  = t >> 6;        // 0..7  wave-uniform: A slice (8k), hidden slice (16k), fin row
  const int cq   = t & 127;       // big col-quad -> cols 4cq..4cq+3
  const int ksB  = t >> 7;        // 0..3  wave-uniform: big k-slice (32k)
  const int rE   = t >> 6;        // epilogue row (wave-uniform)
  const int hE   = t & 63;        // epilogue h

  // ---- register-stationary weight slices (208 VGPRs total) ----
  float2 winR[8];
#pragma unroll
  for (int j = 0; j < 8; ++j)
    winR[j] = *(const float2*)(W_in + (8*ks8 + j)*HHD + 2*cp);
  float2 wh1[16], wh2[16];
#pragma unroll
  for (int j = 0; j < 16; ++j) {
    wh1[j] = *(const float2*)(W_h + (16*ks8 + j)*HHD + 2*cp);
    wh2[j] = *(const float2*)(W_h + HHD*HHD + (16*ks8 + j)*HHD + 2*cp);
  }
  float4 wout[32];
#pragma unroll
  for (int j = 0; j < 32; ++j)
    wout[j] = *(const float4*)(W_out + (32*ksB + j)*(HD*CC) + 4*cq);

  const float2 binv  = *(const float2*)(b_in + 2*cp);
  const float2 bh1v  = *(const float2*)(b_h + 2*cp);
  const float2 bh2v  = *(const float2*)(b_h + HHD + 2*cp);
  const float  boutv = b_out[t];

  // ---- z0 = coeffs[:,0] @ W_init + b_init ; thread owns (rE, hE) ----
  float z0, kacc = 0.f;
  {
    const float* cf = coeffs + (size_t)(row0 + rE) * (TT*CC);
    float a = b_init[hE];
#pragma unroll
    for (int c = 0; c < CC; ++c) a = fmaf(cf[c], W_init[c*HD + hE], a);
    z0 = a;
    sZs[rE][hE] = a;
  }

  // ---- prime all partial buffers with their bias ----
  *(float2*)&pA[ks8][2*cp] = binv;
  *(float2*)&p1[ks8][2*cp] = bh1v;
  *(float2*)&p2[ks8][2*cp] = bh2v;
#pragma unroll
  for (int r = 0; r < MROWS; ++r) pB[r][t + (t>>3)] = boutv;
  __syncthreads();

  for (int step = 0; step < TT-1; ++step) {
    const float dti = times[step+1] - times[step];
    if (t < 64) {   // same phase as s=0 A_adds: sDx readers are >=1 barrier away
      const int r = t >> 3, c = t & 7;
      const float* cf = coeffs + (size_t)(row0 + r)*(TT*CC) + step*CC + c;
      sDx[r][c] = (cf[CC] - cf[0]) / dti;
    }

#pragma unroll
    for (int s = 0; s < 4; ++s) {
      // ---- phase 1: layer A adds (+ rebias pB, idle here) ----
      {
        const int kb = 8*ks8;
#pragma unroll
        for (int r = 0; r < MROWS; ++r) {
          const float4 za = *(const float4*)&sZs[r][kb];
          const float4 zb = *(const float4*)&sZs[r][kb+4];
          float a0 = 0.f, a1 = 0.f;
          a0 = fmaf(za.x, winR[0].x, a0); a1 = fmaf(za.x, winR[0].y, a1);
          a0 = fmaf(za.y, winR[1].x, a0); a1 = fmaf(za.y, winR[1].y, a1);
          a0 = fmaf(za.z, winR[2].x, a0); a1 = fmaf(za.z, winR[2].y, a1);
          a0 = fmaf(za.w, winR[3].x, a0); a1 = fmaf(za.w, winR[3].y, a1);
          a0 = fmaf(zb.x, winR[4].x, a0); a1 = fmaf(zb.x, winR[4].y, a1);
          a0 = fmaf(zb.y, winR[5].x, a0); a1 = fmaf(zb.y, winR[5].y, a1);
          a0 = fmaf(zb.z, winR[6].x, a0); a1 = fmaf(zb.z, winR[6].y, a1);
          a0 = fmaf(zb.w, winR[7].x, a0); a1 = fmaf(zb.w, winR[7].y, a1);
          atomicAdd(&pA[r][2*cp],   a0);
          atomicAdd(&pA[r][2*cp+1], a1);
        }
#pragma unroll
        for (int r = 0; r < MROWS; ++r) pB[r][t + (t>>3)] = boutv;
      }
      __syncthreads();
      // ---- phase 2: A finalize (relu) -> sHa ----
      {
        float2 v = *(const float2*)&pA[ks8][2*cp];
        v.x = fmaxf(v.x, 0.f); v.y = fmaxf(v.y, 0.f);
        *(float2*)&sHa[ks8][2*cp] = v;
      }
      __syncthreads();
      // ---- phase 3: hidden1 adds (+ rebias pA) ----
      hidden_adds(wh1, sHa, p1, cp, 16*ks8);
      *(float2*)&pA[ks8][2*cp] = binv;
      __syncthreads();
      // ---- phase 4: h1 finalize -> sHb ----
      {
        float2 v = *(const float2*)&p1[ks8][2*cp];
        v.x = fmaxf(v.x, 0.f); v.y = fmaxf(v.y, 0.f);
        *(float2*)&sHb[ks8][2*cp] = v;
      }
      __syncthreads();
      // ---- phase 5: hidden2 adds (+ rebias p1) ----
      hidden_adds(wh2, sHb, p2, cp, 16*ks8);
      *(float2*)&p1[ks8][2*cp] = bh1v;
      __syncthreads();
      // ---- phase 6: h2 finalize -> sHa ----
      {
        float2 v = *(const float2*)&p2[ks8][2*cp];
        v.x = fmaxf(v.x, 0.f); v.y = fmaxf(v.y, 0.f);
        *(float2*)&sHa[ks8][2*cp] = v;
      }
      __syncthreads();
      // ---- phase 7: big layer adds (+ rebias p2) ----
      {
        const int kb    = 32*ksB;
        const int base9 = 4*cq + (cq >> 1);   // col + col>>3 pad layout
#pragma unroll
        for (int half = 0; half < 2; ++half) {   // rows in 2 passes -> acc stays 16 regs
          float4 acc0 = {0,0,0,0}, acc1 = {0,0,0,0}, acc2 = {0,0,0,0}, acc3 = {0,0,0,0};
#pragma unroll
          for (int j = 0; j < 8; ++j) {
            const float4 w0 = wout[4*j+0], w1 = wout[4*j+1], w2 = wout[4*j+2], w3 = wout[4*j+3];
            const float4 hv0 = *(const float4*)&sHa[4*half+0][kb + 4*j];
            acc0.x = fmaf(hv0.x, w0.x, acc0.x); acc0.y = fmaf(hv0.x, w0.y, acc0.y);
            acc0.z = fmaf(hv0.x, w0.z, acc0.z); acc0.w = fmaf(hv0.x, w0.w, acc0.w);
            acc0.x = fmaf(hv0.y, w1.x, acc0.x); acc0.y = fmaf(hv0.y, w1.y, acc0.y);
            acc0.z = fmaf(hv0.y, w1.z, acc0.z); acc0.w = fmaf(hv0.y, w1.w, acc0.w);
            acc0.x = fmaf(hv0.z, w2.x, acc0.x); acc0.y = fmaf(hv0.z, w2.y, acc0.y);
            acc0.z = fmaf(hv0.z, w2.z, acc0.z); acc0.w = fmaf(hv0.z, w2.w, acc0.w);
            acc0.x = fmaf(hv0.w, w3.x, acc0.x); acc0.y = fmaf(hv0.w, w3.y, acc0.y);
            acc0.z = fmaf(hv0.w, w3.z, acc0.z); acc0.w = fmaf(hv0.w, w3.w, acc0.w);
            const float4 hv1 = *(const float4*)&sHa[4*half+1][kb + 4*j];
            acc1.x = fmaf(hv1.x, w0.x, acc1.x); acc1.y = fmaf(hv1.x, w0.y, acc1.y);
            acc1.z = fmaf(hv1.x, w0.z, acc1.z); acc1.w = fmaf(hv1.x, w0.w, acc1.w);
            acc1.x = fmaf(hv1.y, w1.x, acc1.x); acc1.y = fmaf(hv1.y, w1.y, acc1.y);
            acc1.z = fmaf(hv1.y, w1.z, acc1.z); acc1.w = fmaf(hv1.y, w1.w, acc1.w);
            acc1.x = fmaf(hv1.z, w2.x, acc1.x); acc1.y = fmaf(hv1.z, w2.y, acc1.y);
            acc1.z = fmaf(hv1.z, w2.z, acc1.z); acc1.w = fmaf(hv1.z, w2.w, acc1.w);
            acc1.x = fmaf(hv1.w, w3.x, acc1.x); acc1.y = fmaf(hv1.w, w3.y, acc1.y);
            acc1.z = fmaf(hv1.w, w3.z, acc1.z); acc1.w = fmaf(hv1.w, w3.w, acc1.w);
            const float4 hv2 = *(const float4*)&sHa[4*half+2][kb + 4*j];
            acc2.x = fmaf(hv2.x, w0.x, acc2.x); acc2.y = fmaf(hv2.x, w0.y, acc2.y);
            acc2.z = fmaf(hv2.x, w0.z, acc2.z); acc2.w = fmaf(hv2.x, w0.w, acc2.w);
            acc2.x = fmaf(hv2.y, w1.x, acc2.x); acc2.y = fmaf(hv2.y, w1.y, acc2.y);
            acc2.z = fmaf(hv2.y, w1.z, acc2.z); acc2.w = fmaf(hv2.y, w1.w, acc2.w);
            acc2.x = fmaf(hv2.z, w2.x, acc2.x); acc2.y = fmaf(hv2.z, w2.y, acc2.y);
            acc2.z = fmaf(hv2.z, w2.z, acc2.z); acc2.w = fmaf(hv2.z, w2.w, acc2.w);
            acc2.x = fmaf(hv2.w, w3.x, acc2.x); acc2.y = fmaf(hv2.w, w3.y, acc2.y);
            acc2.z = fmaf(hv2.w, w3.z, acc2.z); acc2.w = fmaf(hv2.w, w3.w, acc2.w);
            const float4 hv3 = *(const float4*)&sHa[4*half+3][kb + 4*j];
            acc3.x = fmaf(hv3.x, w0.x, acc3.x); acc3.y = fmaf(hv3.x, w0.y, acc3.y);
            acc3.z = fmaf(hv3.x, w0.z, acc3.z); acc3.w = fmaf(hv3.x, w0.w, acc3.w);
            acc3.x = fmaf(hv3.y, w1.x, acc3.x); acc3.y = fmaf(hv3.y, w1.y, acc3.y);
            acc3.z = fmaf(hv3.y, w1.z, acc3.z); acc3.w = fmaf(hv3.y, w1.w, acc3.w);
            acc3.x = fmaf(hv3.z, w2.x, acc3.x); acc3.y = fmaf(hv3.z, w2.y, acc3.y);
            acc3.z = fmaf(hv3.z, w2.z, acc3.z); acc3.w = fmaf(hv3.z, w2.w, acc3.w);
            acc3.x = fmaf(hv3.w, w3.x, acc3.x); acc3.y = fmaf(hv3.w, w3.y, acc3.y);
            acc3.z = fmaf(hv3.w, w3.z, acc3.z); acc3.w = fmaf(hv3.w, w3.w, acc3.w);
          }
          float* pr0 = &pB[4*half+0][base9];
          atomicAdd(pr0+0, acc0.x); atomicAdd(pr0+1, acc0.y);
          atomicAdd(pr0+2, acc0.z); atomicAdd(pr0+3, acc0.w);
          float* pr1 = &pB[4*half+1][base9];
          atomicAdd(pr1+0, acc1.x); atomicAdd(pr1+1, acc1.y);
          atomicAdd(pr1+2, acc1.z); atomicAdd(pr1+3, acc1.w);
          float* pr2 = &pB[4*half+2][base9];
          atomicAdd(pr2+0, acc2.x); atomicAdd(pr2+1, acc2.y);
          atomicAdd(pr2+2, acc2.z); atomicAdd(pr2+3, acc2.w);
          float* pr3 = &pB[4*half+3][base9];
          atomicAdd(pr3+0, acc3.x); atomicAdd(pr3+1, acc3.y);
          atomicAdd(pr3+2, acc3.z); atomicAdd(pr3+3, acc3.w);
        }
        *(float2*)&p2[ks8][2*cp] = bh2v;
      }
      __syncthreads();
      // ---- phase 8: epilogue: tanh, einsum with dX, RK update -> sZs ----
      {
        const float* pr = &pB[rE][9*hE];
        const float u0 = pr[0], u1 = pr[1], u2 = pr[2], u3 = pr[3];
        const float u4 = pr[4], u5 = pr[5], u6 = pr[6], u7 = pr[7];
        const float4 d0 = *(const float4*)&sDx[rE][0];   // wave-uniform -> broadcast
        const float4 d1 = *(const float4*)&sDx[rE][4];
        float g = fast_tanh(u0)*d0.x + fast_tanh(u1)*d0.y
                + fast_tanh(u2)*d0.z + fast_tanh(u3)*d0.w
                + fast_tanh(u4)*d1.x + fast_tanh(u5)*d1.y
                + fast_tanh(u6)*d1.z + fast_tanh(u7)*d1.w;
        if (s == 0)      kacc = g;
        else if (s == 3) kacc += g;
        else             kacc += 2.0f * g;
        float zs;
        if (s == 3) {
          z0 = z0 + dti * (1.0f/6.0f) * kacc;
          zs = z0;
        } else {
          zs = z0 + ((s == 2) ? dti : 0.5f * dti) * g;
        }
        sZs[rE][hE] = zs;
      }
      __syncthreads();
    } // stages
  }   // steps

  // ---- readout: logits = zT @ W_read + b_read ; loss + accuracy ----
  if (t < MROWS * OO) {
    const int r = t / OO, o = t % OO;
    float a = b_read[o];
#pragma unroll 8
    for (int k = 0; k < HD; ++k) a = fmaf(sZs[r][k], W_read[k*OO + o], a);
    sLog[r][o] = a;
  }
  __syncthreads();
  if (t < 64) {
    float lv = 0.f, cv = 0.f;
    if (t < MROWS) {
      const int r = t;
      float mx = sLog[r][0]; int am = 0;
#pragma unroll
      for (int o = 1; o < OO; ++o) { const float v = sLog[r][o]; if (v > mx) { mx = v; am = o; } }
      float se = 0.f;
#pragma unroll
      for (int o = 0; o < OO; ++o) se += expf(sLog[r][o] - mx);
      const float lse = mx + logf(se);
      const int yr = yy[row0 + r];
      lv = (lse - sLog[r][yr]) * (1.0f / (float)BB);
      cv = (am == yr) ? 1.0f : 0.0f;
    }
    lv += __shfl_xor(lv, 1); lv += __shfl_xor(lv, 2); lv += __shfl_xor(lv, 4);
    cv += __shfl_xor(cv, 1); cv += __shfl_xor(cv, 2); cv += __shfl_xor(cv, 4);
    if (t == 0) { atomicAdd(&out[0], lv); atomicAdd(&out[1], cv); }
  }
}

extern "C" void kernel_launch(void* const* d_in, const int* in_sizes, int n_in,
                              void* d_out, int out_size, void* d_ws, size_t ws_size,
                              hipStream_t stream) {
  const float* coeffs = (const float*)d_in[0];
  const int*   y      = (const int*)  d_in[1];
  const float* times  = (const float*)d_in[2];
  const float* W_init = (const float*)d_in[3];
  const float* b_init = (const float*)d_in[4];
  const float* W_in   = (const float*)d_in[5];
  const float* b_in   = (const float*)d_in[6];
  const float* W_h    = (const float*)d_in[7];
  const float* b_h    = (const float*)d_in[8];
  const float* W_out  = (const float*)d_in[9];
  const float* b_out  = (const float*)d_in[10];
  const float* W_read = (const float*)d_in[11];
  const float* b_read = (const float*)d_in[12];
  float* out = (float*)d_out;

  zero_out_k<<<1, 64, 0, stream>>>(out);   // d_out is poisoned 0xAA before every replay
  cde_main<<<BB/MROWS, NTHR, 0, stream>>>(coeffs, y, times, W_init, b_init,
                                          W_in, b_in, W_h, b_h, W_out, b_out,
                                          W_read, b_read, out);
}